// Round 1
// baseline (835.293 us; speedup 1.0000x reference)
//
#include <hip/hip_runtime.h>

typedef __attribute__((ext_vector_type(8))) _Float16 half8;
typedef __attribute__((ext_vector_type(4))) _Float16 half4v;
typedef __attribute__((ext_vector_type(4))) float f32x4;

__device__ __forceinline__ void gll16(const void* g, void* l) {
  __builtin_amdgcn_global_load_lds(
      (const __attribute__((address_space(1))) unsigned int*)g,
      (__attribute__((address_space(3))) unsigned int*)l, 16, 0, 0);
}

// ---------------- LayerNorm + fp16 cast: one block per row of C=1024 ----------------
__global__ __launch_bounds__(256) void ln_cast_f16(
    const float* __restrict__ x, const float* __restrict__ g,
    const float* __restrict__ b, _Float16* __restrict__ y) {
  const int C = 1024;
  size_t row = blockIdx.x;
  int t = threadIdx.x;
  const float4* xr = (const float4*)(x + row * C);
  float4 v = xr[t];
  float s = v.x + v.y + v.z + v.w;
  float s2 = v.x * v.x + v.y * v.y + v.z * v.z + v.w * v.w;
#pragma unroll
  for (int off = 1; off < 64; off <<= 1) {
    s += __shfl_xor(s, off, 64);
    s2 += __shfl_xor(s2, off, 64);
  }
  __shared__ float ps[4], ps2[4];
  int wave = t >> 6, lane = t & 63;
  if (lane == 0) { ps[wave] = s; ps2[wave] = s2; }
  __syncthreads();
  s = ps[0] + ps[1] + ps[2] + ps[3];
  s2 = ps2[0] + ps2[1] + ps2[2] + ps2[3];
  float mu = s * (1.0f / C);
  float var = s2 * (1.0f / C) - mu * mu;
  float rstd = rsqrtf(var + 1e-5f);
  float4 gv = ((const float4*)g)[t];
  float4 bv = ((const float4*)b)[t];
  half4v o;
  o.x = (_Float16)((v.x - mu) * rstd * gv.x + bv.x);
  o.y = (_Float16)((v.y - mu) * rstd * gv.y + bv.y);
  o.z = (_Float16)((v.z - mu) * rstd * gv.z + bv.z);
  o.w = (_Float16)((v.w - mu) * rstd * gv.w + bv.w);
  ((half4v*)(y + row * C))[t] = o;
}

// ---------------- bf16/f16 (2-byte) transpose per batch: [X][C] -> [C][X] ----------------
__global__ __launch_bounds__(256) void transpose16(
    const unsigned short* __restrict__ in, unsigned short* __restrict__ out) {
  const int X = 8192, C = 1024;
  __shared__ unsigned short tile[64][65];
  int bz = blockIdx.z;
  const unsigned short* ib = in + (size_t)bz * X * C;
  unsigned short* ob = out + (size_t)bz * X * C;
  int r0 = blockIdx.x * 64;  // X dim
  int c0 = blockIdx.y * 64;  // C dim
  int tx = threadIdx.x & 63;
  int ty = threadIdx.x >> 6;  // 0..3
#pragma unroll
  for (int j = 0; j < 16; ++j) {
    int r = ty + j * 4;
    tile[r][tx] = ib[(size_t)(r0 + r) * C + c0 + tx];
  }
  __syncthreads();
#pragma unroll
  for (int j = 0; j < 16; ++j) {
    int c = ty + j * 4;
    ob[(size_t)(c0 + c) * X + r0 + tx] = tile[tx][c];
  }
}

// ---------------- fp16 GEMM, C = A[M,K] @ B[N,K]^T  (both K-contiguous) ----------------
// 128x128 tile, 256 threads (4 waves, 2x2), BK=32, mfma_f32_16x16x32_f16.
// LDS layout [kgrp(4)][row(128)][8 halfs] matches global_load_lds lane order
// and makes fragment ds_read_b128 conflict-free.
__global__ __launch_bounds__(256) void gemm_bt_f16(
    const _Float16* __restrict__ A,   // [Z][M][K]
    const _Float16* __restrict__ Bm,  // [Z][N][K]
    float* __restrict__ Cm,           // [Z][M][N]
    int M, int N, int K,
    const float* __restrict__ colscale,  // [Z][N] or null
    float scale,
    const float* __restrict__ residual)  // [Z][M][N] or null
{
  int bz = blockIdx.z;
  const _Float16* Ab = A + (size_t)bz * M * K;
  const _Float16* Bb = Bm + (size_t)bz * N * K;
  float* Cb = Cm + (size_t)bz * M * N;

  __shared__ _Float16 lA[128 * 32];
  __shared__ _Float16 lB[128 * 32];

  int tid = threadIdx.x;
  int wave = tid >> 6, lane = tid & 63;
  int wm = wave >> 1, wn = wave & 1;
  int m0 = blockIdx.y * 128, n0 = blockIdx.x * 128;

  f32x4 acc[4][4];
  f32x4 zero = {0.f, 0.f, 0.f, 0.f};
#pragma unroll
  for (int i = 0; i < 4; ++i)
#pragma unroll
    for (int j = 0; j < 4; ++j) acc[i][j] = zero;

  // Two staging segments per wave; seg = {kchunk[1:0], rowhalf}
  int seg0 = wave * 2, seg1 = wave * 2 + 1;
  int row0 = (seg0 & 1) * 64 + lane, kc0 = seg0 >> 1;
  int row1 = (seg1 & 1) * 64 + lane, kc1 = seg1 >> 1;

  const _Float16* gA0 = Ab + (size_t)(m0 + row0) * K + kc0 * 8;
  const _Float16* gA1 = Ab + (size_t)(m0 + row1) * K + kc1 * 8;
  const _Float16* gB0 = Bb + (size_t)(n0 + row0) * K + kc0 * 8;
  const _Float16* gB1 = Bb + (size_t)(n0 + row1) * K + kc1 * 8;
  _Float16* dA0 = &lA[seg0 * 512 + lane * 8];
  _Float16* dA1 = &lA[seg1 * 512 + lane * 8];
  _Float16* dB0 = &lB[seg0 * 512 + lane * 8];
  _Float16* dB1 = &lB[seg1 * 512 + lane * 8];

  int kg = lane >> 4, lr = lane & 15;

  for (int k0 = 0; k0 < K; k0 += 32) {
    __syncthreads();
    gll16(gA0 + k0, dA0);
    gll16(gA1 + k0, dA1);
    gll16(gB0 + k0, dB0);
    gll16(gB1 + k0, dB1);
    __syncthreads();
    half8 af[4], bfr[4];
#pragma unroll
    for (int t = 0; t < 4; ++t) {
      int m = wm * 64 + t * 16 + lr;
      af[t] = *(const half8*)&lA[kg * 1024 + m * 8];
      int n = wn * 64 + t * 16 + lr;
      bfr[t] = *(const half8*)&lB[kg * 1024 + n * 8];
    }
#pragma unroll
    for (int t = 0; t < 4; ++t)
#pragma unroll
      for (int u = 0; u < 4; ++u)
        acc[t][u] = __builtin_amdgcn_mfma_f32_16x16x32_f16(af[t], bfr[u], acc[t][u], 0, 0, 0);
  }

  // epilogue: D element (row = quad*4+r, col = lane&15) per 16x16 tile
  int cq = lane >> 4, cn = lane & 15;
  const float* csb = colscale ? colscale + (size_t)bz * N : nullptr;
  const float* rb = residual ? residual + (size_t)bz * M * N : nullptr;
#pragma unroll
  for (int u = 0; u < 4; ++u) {
    int gn = n0 + wn * 64 + u * 16 + cn;
    float cs = scale * (csb ? csb[gn] : 1.0f);
#pragma unroll
    for (int t = 0; t < 4; ++t) {
      int gm = m0 + wm * 64 + t * 16 + cq * 4;
#pragma unroll
      for (int r = 0; r < 4; ++r) {
        size_t idx = (size_t)(gm + r) * N + gn;
        float val = acc[t][u][r] * cs;
        if (rb) val += rb[idx];
        Cb[idx] = val;
      }
    }
  }
}

// ---------------- softmax over X=8192 with threshold-sparsify + renorm ----------------
__global__ __launch_bounds__(256) void softmax_thresh(
    const float* __restrict__ S, _Float16* __restrict__ A) {
  const int X = 8192;
  size_t row = blockIdx.x;
  const float4* sr = (const float4*)(S + row * X);
  int t = threadIdx.x;
  int wave = t >> 6, lane = t & 63;
  __shared__ float sh[4];
  float4 v[8];
#pragma unroll
  for (int j = 0; j < 8; ++j) v[j] = sr[t + j * 256];

  float m = -1e30f;
#pragma unroll
  for (int j = 0; j < 8; ++j)
    m = fmaxf(m, fmaxf(fmaxf(v[j].x, v[j].y), fmaxf(v[j].z, v[j].w)));
#pragma unroll
  for (int off = 1; off < 64; off <<= 1) m = fmaxf(m, __shfl_xor(m, off, 64));
  if (lane == 0) sh[wave] = m;
  __syncthreads();
  m = fmaxf(fmaxf(sh[0], sh[1]), fmaxf(sh[2], sh[3]));
  __syncthreads();

  float l = 0.f;
#pragma unroll
  for (int j = 0; j < 8; ++j) {
    v[j].x = __expf(v[j].x - m);
    v[j].y = __expf(v[j].y - m);
    v[j].z = __expf(v[j].z - m);
    v[j].w = __expf(v[j].w - m);
    l += v[j].x + v[j].y + v[j].z + v[j].w;
  }
#pragma unroll
  for (int off = 1; off < 64; off <<= 1) l += __shfl_xor(l, off, 64);
  if (lane == 0) sh[wave] = l;
  __syncthreads();
  l = sh[0] + sh[1] + sh[2] + sh[3];
  __syncthreads();

  float thr = 0.0005f * l;  // attn < 5e-4  <=>  e < 5e-4 * l
  float ks = 0.f;
#pragma unroll
  for (int j = 0; j < 8; ++j) {
    v[j].x = (v[j].x >= thr) ? v[j].x : 0.f;
    v[j].y = (v[j].y >= thr) ? v[j].y : 0.f;
    v[j].z = (v[j].z >= thr) ? v[j].z : 0.f;
    v[j].w = (v[j].w >= thr) ? v[j].w : 0.f;
    ks += v[j].x + v[j].y + v[j].z + v[j].w;
  }
#pragma unroll
  for (int off = 1; off < 64; off <<= 1) ks += __shfl_xor(ks, off, 64);
  if (lane == 0) sh[wave] = ks;
  __syncthreads();
  ks = sh[0] + sh[1] + sh[2] + sh[3];

  float inv = 1.0f / ks;  // attn/sum(kept) == e/ksum
  _Float16* ar = A + row * X;
#pragma unroll
  for (int j = 0; j < 8; ++j) {
    half4v o;
    o.x = (_Float16)(v[j].x * inv);
    o.y = (_Float16)(v[j].y * inv);
    o.z = (_Float16)(v[j].z * inv);
    o.w = (_Float16)(v[j].w * inv);
    ((half4v*)ar)[t + j * 256] = o;
  }
}

extern "C" void kernel_launch(void* const* d_in, const int* in_sizes, int n_in,
                              void* d_out, int out_size, void* d_ws, size_t ws_size,
                              hipStream_t stream) {
  const int B = 4, P = 1024, X = 8192, C = 1024;
  const float* feat  = (const float*)d_in[0];
  const float* mem_k = (const float*)d_in[1];
  const float* mem_v = (const float*)d_in[2];
  const float* mem_c = (const float*)d_in[3];  // [B,X,1] -> flat [B*X]
  // d_in[4] = mem_attn (unused by reference)
  const float* g_q = (const float*)d_in[5];
  const float* b_q = (const float*)d_in[6];
  const float* g_k = (const float*)d_in[7];
  const float* b_k = (const float*)d_in[8];
  const float* g_v = (const float*)d_in[9];
  const float* b_v = (const float*)d_in[10];

  char* ws = (char*)d_ws;
  const size_t MB = 1024 * 1024;
  _Float16* q16 = (_Float16*)(ws + 0);          // 8 MB  [B][P][C]
  _Float16* k16 = (_Float16*)(ws + 8 * MB);     // 64 MB [B][X][C]
  _Float16* v16 = (_Float16*)(ws + 72 * MB);    // 64 MB [B][X][C]
  _Float16* vT  = (_Float16*)(ws + 136 * MB);   // 64 MB [B][C][X]
  float*    S   = (float*)(ws + 200 * MB);      // 128 MB [B][P][X]
  _Float16* attn = v16;  // reuse v16 after transpose; 64 MB [B][P][X]

  ln_cast_f16<<<B * P, 256, 0, stream>>>(feat, g_q, b_q, q16);
  ln_cast_f16<<<B * X, 256, 0, stream>>>(mem_k, g_k, b_k, k16);
  ln_cast_f16<<<B * X, 256, 0, stream>>>(mem_v, g_v, b_v, v16);
  transpose16<<<dim3(X / 64, C / 64, B), 256, 0, stream>>>(
      (const unsigned short*)v16, (unsigned short*)vT);
  // S = (q . k^T / 32) * c_x
  gemm_bt_f16<<<dim3(X / 128, P / 128, B), 256, 0, stream>>>(
      q16, k16, S, P, X, C, mem_c, 0.03125f, nullptr);
  softmax_thresh<<<B * P, 256, 0, stream>>>(S, attn);
  // out = attn @ v + feat
  gemm_bt_f16<<<dim3(C / 128, P / 128, B), 256, 0, stream>>>(
      attn, vT, (float*)d_out, P, C, X, nullptr, 1.0f, feat);
}

// Round 2
// 573.316 us; speedup vs baseline: 1.4570x; 1.4570x over previous
//
#include <hip/hip_runtime.h>

typedef __attribute__((ext_vector_type(8))) _Float16 half8;
typedef __attribute__((ext_vector_type(4))) _Float16 half4v;
typedef __attribute__((ext_vector_type(4))) float f32x4;

__device__ __forceinline__ void gll16(const void* g, void* l) {
  __builtin_amdgcn_global_load_lds(
      (const __attribute__((address_space(1))) unsigned int*)g,
      (__attribute__((address_space(3))) unsigned int*)l, 16, 0, 0);
}

// ---------------- LayerNorm + fp16 cast: one block per row of C=1024 ----------------
__global__ __launch_bounds__(256) void ln_cast_f16(
    const float* __restrict__ x, const float* __restrict__ g,
    const float* __restrict__ b, _Float16* __restrict__ y) {
  const int C = 1024;
  size_t row = blockIdx.x;
  int t = threadIdx.x;
  const float4* xr = (const float4*)(x + row * C);
  float4 v = xr[t];
  float s = v.x + v.y + v.z + v.w;
  float s2 = v.x * v.x + v.y * v.y + v.z * v.z + v.w * v.w;
#pragma unroll
  for (int off = 1; off < 64; off <<= 1) {
    s += __shfl_xor(s, off, 64);
    s2 += __shfl_xor(s2, off, 64);
  }
  __shared__ float ps[4], ps2[4];
  int wave = t >> 6, lane = t & 63;
  if (lane == 0) { ps[wave] = s; ps2[wave] = s2; }
  __syncthreads();
  s = ps[0] + ps[1] + ps[2] + ps[3];
  s2 = ps2[0] + ps2[1] + ps2[2] + ps2[3];
  float mu = s * (1.0f / C);
  float var = s2 * (1.0f / C) - mu * mu;
  float rstd = rsqrtf(var + 1e-5f);
  float4 gv = ((const float4*)g)[t];
  float4 bv = ((const float4*)b)[t];
  half4v o;
  o.x = (_Float16)((v.x - mu) * rstd * gv.x + bv.x);
  o.y = (_Float16)((v.y - mu) * rstd * gv.y + bv.y);
  o.z = (_Float16)((v.z - mu) * rstd * gv.z + bv.z);
  o.w = (_Float16)((v.w - mu) * rstd * gv.w + bv.w);
  ((half4v*)(y + row * C))[t] = o;
}

// ---------------- fp16 GEMM, C = A[M,K] @ B[N,K]^T  (both K-contiguous) ----------------
// 128x128 tile, 256 threads (4 waves, 2x2), BK=32, mfma_f32_16x16x32_f16.
__global__ __launch_bounds__(256) void gemm_bt_f16(
    const _Float16* __restrict__ A,   // [Z][M][K]
    const _Float16* __restrict__ Bm,  // [Z][N][K]
    float* __restrict__ Cm,           // [Z][M][N]
    int M, int N, int K,
    const float* __restrict__ colscale,  // [Z][N] or null
    float scale)
{
  int bz = blockIdx.z;
  const _Float16* Ab = A + (size_t)bz * M * K;
  const _Float16* Bb = Bm + (size_t)bz * N * K;
  float* Cb = Cm + (size_t)bz * M * N;

  __shared__ _Float16 lA[128 * 32];
  __shared__ _Float16 lB[128 * 32];

  int tid = threadIdx.x;
  int wave = tid >> 6, lane = tid & 63;
  int wm = wave >> 1, wn = wave & 1;
  int m0 = blockIdx.y * 128, n0 = blockIdx.x * 128;

  f32x4 acc[4][4];
  f32x4 zero = {0.f, 0.f, 0.f, 0.f};
#pragma unroll
  for (int i = 0; i < 4; ++i)
#pragma unroll
    for (int j = 0; j < 4; ++j) acc[i][j] = zero;

  int seg0 = wave * 2, seg1 = wave * 2 + 1;
  int row0 = (seg0 & 1) * 64 + lane, kc0 = seg0 >> 1;
  int row1 = (seg1 & 1) * 64 + lane, kc1 = seg1 >> 1;

  const _Float16* gA0 = Ab + (size_t)(m0 + row0) * K + kc0 * 8;
  const _Float16* gA1 = Ab + (size_t)(m0 + row1) * K + kc1 * 8;
  const _Float16* gB0 = Bb + (size_t)(n0 + row0) * K + kc0 * 8;
  const _Float16* gB1 = Bb + (size_t)(n0 + row1) * K + kc1 * 8;
  _Float16* dA0 = &lA[seg0 * 512 + lane * 8];
  _Float16* dA1 = &lA[seg1 * 512 + lane * 8];
  _Float16* dB0 = &lB[seg0 * 512 + lane * 8];
  _Float16* dB1 = &lB[seg1 * 512 + lane * 8];

  int kg = lane >> 4, lr = lane & 15;

  for (int k0 = 0; k0 < K; k0 += 32) {
    __syncthreads();
    gll16(gA0 + k0, dA0);
    gll16(gA1 + k0, dA1);
    gll16(gB0 + k0, dB0);
    gll16(gB1 + k0, dB1);
    __syncthreads();
    half8 af[4], bfr[4];
#pragma unroll
    for (int t = 0; t < 4; ++t) {
      int m = wm * 64 + t * 16 + lr;
      af[t] = *(const half8*)&lA[kg * 1024 + m * 8];
      int n = wn * 64 + t * 16 + lr;
      bfr[t] = *(const half8*)&lB[kg * 1024 + n * 8];
    }
#pragma unroll
    for (int t = 0; t < 4; ++t)
#pragma unroll
      for (int u = 0; u < 4; ++u)
        acc[t][u] = __builtin_amdgcn_mfma_f32_16x16x32_f16(af[t], bfr[u], acc[t][u], 0, 0, 0);
  }

  int cq = lane >> 4, cn = lane & 15;
  const float* csb = colscale ? colscale + (size_t)bz * N : nullptr;
#pragma unroll
  for (int u = 0; u < 4; ++u) {
    int gn = n0 + wn * 64 + u * 16 + cn;
    float cs = scale * (csb ? csb[gn] : 1.0f);
#pragma unroll
    for (int t = 0; t < 4; ++t) {
      int gm = m0 + wm * 64 + t * 16 + cq * 4;
#pragma unroll
      for (int r = 0; r < 4; ++r) {
        size_t idx = (size_t)(gm + r) * N + gn;
        Cb[idx] = acc[t][u][r] * cs;
      }
    }
  }
}

// ------- softmax over X=8192 + threshold + renorm + COMPACT kept (x, w) pairs -------
// entries[row][k] = (x << 16) | fp16bits(weight); counts[row] = #kept (<= 2000)
__global__ __launch_bounds__(256) void softmax_compact(
    const float* __restrict__ S, unsigned* __restrict__ entries,
    int* __restrict__ counts) {
  const int X = 8192;
  size_t row = blockIdx.x;
  const float4* sr = (const float4*)(S + row * X);
  int t = threadIdx.x;
  int wave = t >> 6, lane = t & 63;
  __shared__ float sh[4];
  __shared__ int scnt;
  float4 v[8];
#pragma unroll
  for (int j = 0; j < 8; ++j) v[j] = sr[t + j * 256];

  float m = -1e30f;
#pragma unroll
  for (int j = 0; j < 8; ++j)
    m = fmaxf(m, fmaxf(fmaxf(v[j].x, v[j].y), fmaxf(v[j].z, v[j].w)));
#pragma unroll
  for (int off = 1; off < 64; off <<= 1) m = fmaxf(m, __shfl_xor(m, off, 64));
  if (lane == 0) sh[wave] = m;
  __syncthreads();
  m = fmaxf(fmaxf(sh[0], sh[1]), fmaxf(sh[2], sh[3]));
  __syncthreads();

  float l = 0.f;
#pragma unroll
  for (int j = 0; j < 8; ++j) {
    v[j].x = __expf(v[j].x - m);
    v[j].y = __expf(v[j].y - m);
    v[j].z = __expf(v[j].z - m);
    v[j].w = __expf(v[j].w - m);
    l += v[j].x + v[j].y + v[j].z + v[j].w;
  }
#pragma unroll
  for (int off = 1; off < 64; off <<= 1) l += __shfl_xor(l, off, 64);
  if (lane == 0) sh[wave] = l;
  __syncthreads();
  l = sh[0] + sh[1] + sh[2] + sh[3];
  __syncthreads();

  float thr = 0.0005f * l;  // attn < 5e-4  <=>  e < 5e-4 * l
  float ks = 0.f;
#pragma unroll
  for (int j = 0; j < 8; ++j) {
    v[j].x = (v[j].x >= thr) ? v[j].x : 0.f;
    v[j].y = (v[j].y >= thr) ? v[j].y : 0.f;
    v[j].z = (v[j].z >= thr) ? v[j].z : 0.f;
    v[j].w = (v[j].w >= thr) ? v[j].w : 0.f;
    ks += v[j].x + v[j].y + v[j].z + v[j].w;
  }
#pragma unroll
  for (int off = 1; off < 64; off <<= 1) ks += __shfl_xor(ks, off, 64);
  if (lane == 0) sh[wave] = ks;
  __syncthreads();
  if (t == 0) scnt = 0;
  __syncthreads();
  ks = sh[0] + sh[1] + sh[2] + sh[3];

  float inv = 1.0f / ks;
  unsigned* er = entries + row * 2048;
#pragma unroll
  for (int j = 0; j < 8; ++j) {
    int cbase = (t + j * 256) * 4;
    float vals[4] = {v[j].x, v[j].y, v[j].z, v[j].w};
#pragma unroll
    for (int c = 0; c < 4; ++c) {
      if (vals[c] > 0.f) {
        int pos = atomicAdd(&scnt, 1);
        _Float16 h = (_Float16)(vals[c] * inv);
        unsigned short hb;
        __builtin_memcpy(&hb, &h, 2);
        er[pos] = ((unsigned)(cbase + c) << 16) | hb;
      }
    }
  }
  __syncthreads();
  if (t == 0) counts[row] = scnt;
}

// ------- sparse gather: out[row][:] = feat[row][:] + sum_kept w * v16[x][:] -------
__global__ __launch_bounds__(256) void gather_pv(
    const unsigned* __restrict__ entries, const int* __restrict__ counts,
    const _Float16* __restrict__ v16, const float* __restrict__ feat,
    float* __restrict__ out) {
  const int X = 8192, C = 1024;
  int row = blockIdx.x;          // b*1024 + p
  int b = row >> 10;
  const unsigned* er = entries + (size_t)row * 2048;
  int cnt = counts[row];
  int t = threadIdx.x;
  const _Float16* vb = v16 + (size_t)b * X * C;

  float4 acc = {0.f, 0.f, 0.f, 0.f};
  __shared__ unsigned se[256];

  for (int base = 0; base < cnt; base += 256) {
    int n = min(256, cnt - base);
    __syncthreads();
    if (t < n) se[t] = er[base + t];
    __syncthreads();
#pragma unroll 8
    for (int j = 0; j < n; ++j) {
      unsigned e = se[j];
      int x = e >> 16;
      unsigned short hb = (unsigned short)(e & 0xffff);
      _Float16 h;
      __builtin_memcpy(&h, &hb, 2);
      float w = (float)h;
      half4v vv = *(const half4v*)(vb + (size_t)x * C + t * 4);
      acc.x += w * (float)vv.x;
      acc.y += w * (float)vv.y;
      acc.z += w * (float)vv.z;
      acc.w += w * (float)vv.w;
    }
  }
  size_t o = (size_t)row * C + t * 4;
  float4 f = *(const float4*)(feat + o);
  acc.x += f.x; acc.y += f.y; acc.z += f.z; acc.w += f.w;
  *(float4*)(out + o) = acc;
}

extern "C" void kernel_launch(void* const* d_in, const int* in_sizes, int n_in,
                              void* d_out, int out_size, void* d_ws, size_t ws_size,
                              hipStream_t stream) {
  const int B = 4, P = 1024, X = 8192, C = 1024;
  const float* feat  = (const float*)d_in[0];
  const float* mem_k = (const float*)d_in[1];
  const float* mem_v = (const float*)d_in[2];
  const float* mem_c = (const float*)d_in[3];  // [B,X,1] -> flat [B*X]
  const float* g_q = (const float*)d_in[5];
  const float* b_q = (const float*)d_in[6];
  const float* g_k = (const float*)d_in[7];
  const float* b_k = (const float*)d_in[8];
  const float* g_v = (const float*)d_in[9];
  const float* b_v = (const float*)d_in[10];

  char* ws = (char*)d_ws;
  const size_t MB = 1024 * 1024;
  _Float16* q16 = (_Float16*)(ws + 0);           // 8 MB   [B][P][C]
  _Float16* k16 = (_Float16*)(ws + 8 * MB);      // 64 MB  [B][X][C]
  _Float16* v16 = (_Float16*)(ws + 72 * MB);     // 64 MB  [B][X][C]
  float*    S   = (float*)(ws + 136 * MB);       // 128 MB [B][P][X]
  unsigned* entries = (unsigned*)(ws + 264 * MB);// 32 MB  [B*P][2048]
  int*      counts  = (int*)(ws + 296 * MB);     // 16 KB  [B*P]

  ln_cast_f16<<<B * P, 256, 0, stream>>>(feat, g_q, b_q, q16);
  ln_cast_f16<<<B * X, 256, 0, stream>>>(mem_k, g_k, b_k, k16);
  ln_cast_f16<<<B * X, 256, 0, stream>>>(mem_v, g_v, b_v, v16);
  // S = (q . k^T / 32) * c_x
  gemm_bt_f16<<<dim3(X / 128, P / 128, B), 256, 0, stream>>>(
      q16, k16, S, P, X, C, mem_c, 0.03125f);
  softmax_compact<<<B * P, 256, 0, stream>>>(S, entries, counts);
  gather_pv<<<B * P, 256, 0, stream>>>(entries, counts, v16, feat, (float*)d_out);
}

// Round 3
// 538.335 us; speedup vs baseline: 1.5516x; 1.0650x over previous
//
#include <hip/hip_runtime.h>

typedef __attribute__((ext_vector_type(8))) _Float16 half8;
typedef __attribute__((ext_vector_type(4))) _Float16 half4v;
typedef __attribute__((ext_vector_type(4))) float f32x4;

__device__ __forceinline__ void gll16(const void* g, void* l) {
  __builtin_amdgcn_global_load_lds(
      (const __attribute__((address_space(1))) unsigned int*)g,
      (__attribute__((address_space(3))) unsigned int*)l, 16, 0, 0);
}

__device__ __forceinline__ float h2f(unsigned short hb) {
  _Float16 h;
  __builtin_memcpy(&h, &hb, 2);
  return (float)h;
}

// ---------------- LayerNorm + fp16 cast: one block per row of C=1024 ----------------
__global__ __launch_bounds__(256) void ln_cast_f16(
    const float* __restrict__ x, const float* __restrict__ g,
    const float* __restrict__ b, _Float16* __restrict__ y) {
  const int C = 1024;
  size_t row = blockIdx.x;
  int t = threadIdx.x;
  const float4* xr = (const float4*)(x + row * C);
  float4 v = xr[t];
  float s = v.x + v.y + v.z + v.w;
  float s2 = v.x * v.x + v.y * v.y + v.z * v.z + v.w * v.w;
#pragma unroll
  for (int off = 1; off < 64; off <<= 1) {
    s += __shfl_xor(s, off, 64);
    s2 += __shfl_xor(s2, off, 64);
  }
  __shared__ float ps[4], ps2[4];
  int wave = t >> 6, lane = t & 63;
  if (lane == 0) { ps[wave] = s; ps2[wave] = s2; }
  __syncthreads();
  s = ps[0] + ps[1] + ps[2] + ps[3];
  s2 = ps2[0] + ps2[1] + ps2[2] + ps2[3];
  float mu = s * (1.0f / C);
  float var = s2 * (1.0f / C) - mu * mu;
  float rstd = rsqrtf(var + 1e-5f);
  float4 gv = ((const float4*)g)[t];
  float4 bv = ((const float4*)b)[t];
  half4v o;
  o.x = (_Float16)((v.x - mu) * rstd * gv.x + bv.x);
  o.y = (_Float16)((v.y - mu) * rstd * gv.y + bv.y);
  o.z = (_Float16)((v.z - mu) * rstd * gv.z + bv.z);
  o.w = (_Float16)((v.w - mu) * rstd * gv.w + bv.w);
  ((half4v*)(y + row * C))[t] = o;
}

// -------- QK^T GEMM: S[p][x] = fp16( (q.k/32) * c[x] ), 256x128 tile, 512 thr --------
// M=1024 (P), N=8192 (X), K=1024 (C) per batch. LDS [kg(4)][row][8] chunked layout.
__global__ __launch_bounds__(512) void gemm_qk_f16(
    const _Float16* __restrict__ A,   // [B][1024][1024] q16
    const _Float16* __restrict__ Bm,  // [B][8192][1024] k16
    _Float16* __restrict__ Sm,        // [B][1024][8192]
    const float* __restrict__ conf)   // [B][8192]
{
  const int M = 1024, N = 8192, K = 1024;
  int bz = blockIdx.z;
  const _Float16* Ab = A + (size_t)bz * M * K;
  const _Float16* Bb = Bm + (size_t)bz * N * K;
  _Float16* Sb = Sm + (size_t)bz * M * N;

  __shared__ _Float16 lA[256 * 32];  // 16 KB
  __shared__ _Float16 lB[128 * 32];  // 8 KB

  int tid = threadIdx.x;
  int wave = tid >> 6, lane = tid & 63;
  int wm = wave >> 1, wn = wave & 1;
  int m0 = blockIdx.y * 256, n0 = blockIdx.x * 128;

  f32x4 acc[4][4];
  f32x4 zero = {0.f, 0.f, 0.f, 0.f};
#pragma unroll
  for (int i = 0; i < 4; ++i)
#pragma unroll
    for (int j = 0; j < 4; ++j) acc[i][j] = zero;

  // A staging: 1024 segments (kg*256 + row), this thread does tid and tid+512
  int rA0 = tid & 255, kgA0 = tid >> 8;          // kg 0..1
  int rA1 = rA0, kgA1 = kgA0 + 2;                // kg 2..3
  // B staging: 512 segments (kg*128 + row)
  int rB = tid & 127, kgB = tid >> 7;            // kg 0..3
  const _Float16* gA0 = Ab + (size_t)(m0 + rA0) * K + kgA0 * 8;
  const _Float16* gA1 = Ab + (size_t)(m0 + rA1) * K + kgA1 * 8;
  const _Float16* gB0 = Bb + (size_t)(n0 + rB) * K + kgB * 8;
  _Float16* dA0 = &lA[kgA0 * 2048 + rA0 * 8];
  _Float16* dA1 = &lA[kgA1 * 2048 + rA1 * 8];
  _Float16* dB0 = &lB[kgB * 1024 + rB * 8];

  int kg = lane >> 4, lr = lane & 15;

  for (int k0 = 0; k0 < K; k0 += 32) {
    __syncthreads();
    gll16(gA0 + k0, dA0);
    gll16(gA1 + k0, dA1);
    gll16(gB0 + k0, dB0);
    __syncthreads();
    half8 af[4], bfr[4];
#pragma unroll
    for (int t = 0; t < 4; ++t) {
      int m = wm * 64 + t * 16 + lr;
      af[t] = *(const half8*)&lA[kg * 2048 + m * 8];
      int n = wn * 64 + t * 16 + lr;
      bfr[t] = *(const half8*)&lB[kg * 1024 + n * 8];
    }
#pragma unroll
    for (int t = 0; t < 4; ++t)
#pragma unroll
      for (int u = 0; u < 4; ++u)
        acc[t][u] = __builtin_amdgcn_mfma_f32_16x16x32_f16(af[t], bfr[u], acc[t][u], 0, 0, 0);
  }

  int cq = lane >> 4, cn = lane & 15;
  const float* cb = conf + (size_t)bz * N;
#pragma unroll
  for (int u = 0; u < 4; ++u) {
    int gn = n0 + wn * 64 + u * 16 + cn;
    float cs = 0.03125f * cb[gn];
#pragma unroll
    for (int t = 0; t < 4; ++t) {
      int gm = m0 + wm * 64 + t * 16 + cq * 4;
#pragma unroll
      for (int r = 0; r < 4; ++r)
        Sb[(size_t)(gm + r) * N + gn] = (_Float16)(acc[t][u][r] * cs);
    }
  }
}

// ------- softmax over X=8192 (fp16 S) + threshold + renorm + compact (x, w) -------
__global__ __launch_bounds__(256) void softmax_compact(
    const _Float16* __restrict__ S, unsigned* __restrict__ entries,
    int* __restrict__ counts) {
  const int X = 8192;
  size_t row = blockIdx.x;
  const half8* sr = (const half8*)(S + row * X);
  int t = threadIdx.x;
  int wave = t >> 6, lane = t & 63;
  __shared__ float sh[4];
  __shared__ int scnt;

  float v[32];
#pragma unroll
  for (int j = 0; j < 4; ++j) {
    half8 h = sr[t + j * 256];
#pragma unroll
    for (int c = 0; c < 8; ++c) v[j * 8 + c] = (float)h[c];
  }

  float m = -1e30f;
#pragma unroll
  for (int i = 0; i < 32; ++i) m = fmaxf(m, v[i]);
#pragma unroll
  for (int off = 1; off < 64; off <<= 1) m = fmaxf(m, __shfl_xor(m, off, 64));
  if (lane == 0) sh[wave] = m;
  __syncthreads();
  m = fmaxf(fmaxf(sh[0], sh[1]), fmaxf(sh[2], sh[3]));
  __syncthreads();

  float l = 0.f;
#pragma unroll
  for (int i = 0; i < 32; ++i) {
    v[i] = __expf(v[i] - m);
    l += v[i];
  }
#pragma unroll
  for (int off = 1; off < 64; off <<= 1) l += __shfl_xor(l, off, 64);
  if (lane == 0) sh[wave] = l;
  __syncthreads();
  l = sh[0] + sh[1] + sh[2] + sh[3];
  __syncthreads();

  float thr = 0.0005f * l;  // attn < 5e-4  <=>  e < 5e-4 * l
  float ks = 0.f;
#pragma unroll
  for (int i = 0; i < 32; ++i) {
    v[i] = (v[i] >= thr) ? v[i] : 0.f;
    ks += v[i];
  }
#pragma unroll
  for (int off = 1; off < 64; off <<= 1) ks += __shfl_xor(ks, off, 64);
  if (lane == 0) sh[wave] = ks;
  __syncthreads();
  if (t == 0) scnt = 0;
  __syncthreads();
  ks = sh[0] + sh[1] + sh[2] + sh[3];

  float inv = 1.0f / ks;
  unsigned* er = entries + row * 2048;
#pragma unroll
  for (int j = 0; j < 4; ++j) {
#pragma unroll
    for (int c = 0; c < 8; ++c) {
      float val = v[j * 8 + c];
      if (val > 0.f) {
        int pos = atomicAdd(&scnt, 1);
        _Float16 h = (_Float16)(val * inv);
        unsigned short hb;
        __builtin_memcpy(&hb, &h, 2);
        er[pos] = ((unsigned)((t + j * 256) * 8 + c) << 16) | hb;
      }
    }
  }
  __syncthreads();
  if (t == 0) counts[row] = scnt;
}

// --- sparse gather: out[row][:] = feat[row][:] + sum w * v16[x][:] ---
// 512 threads = 4 entry-streams x 128 lanes x 16B loads; LDS reduce.
__global__ __launch_bounds__(512) void gather_pv(
    const unsigned* __restrict__ entries, const int* __restrict__ counts,
    const _Float16* __restrict__ v16, const float* __restrict__ feat,
    float* __restrict__ out) {
  const int X = 8192, C = 1024;
  int row = blockIdx.x;  // b*1024 + p
  int b = row >> 10;
  int t = threadIdx.x;
  int s = t >> 7;           // stream 0..3
  int c = (t & 127) * 8;    // half index within row

  __shared__ unsigned se[2048];
  __shared__ float red[4][1024];

  int cnt = counts[row];
  const unsigned* er = entries + (size_t)row * 2048;
  for (int i = t; i < cnt; i += 512) se[i] = er[i];
  __syncthreads();

  const _Float16* vb = v16 + (size_t)b * X * C;
  float a0 = 0, a1 = 0, a2 = 0, a3 = 0, a4 = 0, a5 = 0, a6 = 0, a7 = 0;
#pragma unroll 4
  for (int j = s; j < cnt; j += 4) {
    unsigned e = se[j];
    int x = e >> 16;
    float w = h2f((unsigned short)(e & 0xffff));
    half8 vv = *(const half8*)(vb + (size_t)x * C + c);
    a0 += w * (float)vv[0]; a1 += w * (float)vv[1];
    a2 += w * (float)vv[2]; a3 += w * (float)vv[3];
    a4 += w * (float)vv[4]; a5 += w * (float)vv[5];
    a6 += w * (float)vv[6]; a7 += w * (float)vv[7];
  }
  float* rp = &red[s][c];
  rp[0] = a0; rp[1] = a1; rp[2] = a2; rp[3] = a3;
  rp[4] = a4; rp[5] = a5; rp[6] = a6; rp[7] = a7;
  __syncthreads();

  int p = t * 2;
  float2 f = *(const float2*)(feat + (size_t)row * C + p);
  float2 o;
  o.x = red[0][p] + red[1][p] + red[2][p] + red[3][p] + f.x;
  o.y = red[0][p + 1] + red[1][p + 1] + red[2][p + 1] + red[3][p + 1] + f.y;
  *(float2*)(out + (size_t)row * C + p) = o;
}

extern "C" void kernel_launch(void* const* d_in, const int* in_sizes, int n_in,
                              void* d_out, int out_size, void* d_ws, size_t ws_size,
                              hipStream_t stream) {
  const int B = 4, P = 1024, X = 8192, C = 1024;
  const float* feat  = (const float*)d_in[0];
  const float* mem_k = (const float*)d_in[1];
  const float* mem_v = (const float*)d_in[2];
  const float* mem_c = (const float*)d_in[3];  // [B,X,1] -> flat [B*X]
  const float* g_q = (const float*)d_in[5];
  const float* b_q = (const float*)d_in[6];
  const float* g_k = (const float*)d_in[7];
  const float* b_k = (const float*)d_in[8];
  const float* g_v = (const float*)d_in[9];
  const float* b_v = (const float*)d_in[10];

  char* ws = (char*)d_ws;
  const size_t MB = 1024 * 1024;
  _Float16* q16 = (_Float16*)(ws + 0);            // 8 MB   [B][P][C]
  _Float16* k16 = (_Float16*)(ws + 8 * MB);       // 64 MB  [B][X][C]
  _Float16* v16 = (_Float16*)(ws + 72 * MB);      // 64 MB  [B][X][C]
  _Float16* S   = (_Float16*)(ws + 136 * MB);     // 64 MB  [B][P][X] fp16
  unsigned* entries = (unsigned*)(ws + 200 * MB); // 32 MB  [B*P][2048]
  int*      counts  = (int*)(ws + 232 * MB);      // 16 KB  [B*P]

  ln_cast_f16<<<B * P, 256, 0, stream>>>(feat, g_q, b_q, q16);
  ln_cast_f16<<<B * X, 256, 0, stream>>>(mem_k, g_k, b_k, k16);
  ln_cast_f16<<<B * X, 256, 0, stream>>>(mem_v, g_v, b_v, v16);
  gemm_qk_f16<<<dim3(X / 128, P / 256, B), 512, 0, stream>>>(q16, k16, S, mem_c);
  softmax_compact<<<B * P, 256, 0, stream>>>(S, entries, counts);
  gather_pv<<<B * P, 512, 0, stream>>>(entries, counts, v16, feat, (float*)d_out);
}

// Round 4
// 529.616 us; speedup vs baseline: 1.5772x; 1.0165x over previous
//
#include <hip/hip_runtime.h>

typedef __attribute__((ext_vector_type(8))) _Float16 half8;
typedef __attribute__((ext_vector_type(4))) _Float16 half4v;
typedef __attribute__((ext_vector_type(4))) float f32x4;

__device__ __forceinline__ void gll16(const void* g, void* l) {
  __builtin_amdgcn_global_load_lds(
      (const __attribute__((address_space(1))) unsigned int*)g,
      (__attribute__((address_space(3))) unsigned int*)l, 16, 0, 0);
}

__device__ __forceinline__ float h2f(unsigned short hb) {
  _Float16 h;
  __builtin_memcpy(&h, &hb, 2);
  return (float)h;
}

// ---------------- LayerNorm + fp16 cast: one block per row of C=1024 ----------------
__global__ __launch_bounds__(256) void ln_cast_f16(
    const float* __restrict__ x, const float* __restrict__ g,
    const float* __restrict__ b, _Float16* __restrict__ y) {
  const int C = 1024;
  size_t row = blockIdx.x;
  int t = threadIdx.x;
  const float4* xr = (const float4*)(x + row * C);
  float4 v = xr[t];
  float s = v.x + v.y + v.z + v.w;
  float s2 = v.x * v.x + v.y * v.y + v.z * v.z + v.w * v.w;
#pragma unroll
  for (int off = 1; off < 64; off <<= 1) {
    s += __shfl_xor(s, off, 64);
    s2 += __shfl_xor(s2, off, 64);
  }
  __shared__ float ps[4], ps2[4];
  int wave = t >> 6, lane = t & 63;
  if (lane == 0) { ps[wave] = s; ps2[wave] = s2; }
  __syncthreads();
  s = ps[0] + ps[1] + ps[2] + ps[3];
  s2 = ps2[0] + ps2[1] + ps2[2] + ps2[3];
  float mu = s * (1.0f / C);
  float var = s2 * (1.0f / C) - mu * mu;
  float rstd = rsqrtf(var + 1e-5f);
  float4 gv = ((const float4*)g)[t];
  float4 bv = ((const float4*)b)[t];
  half4v o;
  o.x = (_Float16)((v.x - mu) * rstd * gv.x + bv.x);
  o.y = (_Float16)((v.y - mu) * rstd * gv.y + bv.y);
  o.z = (_Float16)((v.z - mu) * rstd * gv.z + bv.z);
  o.w = (_Float16)((v.w - mu) * rstd * gv.w + bv.w);
  ((half4v*)(y + row * C))[t] = o;
}

// ------------- LayerNorm + int8 quant (per-row scale): one block per row -------------
__global__ __launch_bounds__(256) void ln_cast_i8(
    const float* __restrict__ x, const float* __restrict__ g,
    const float* __restrict__ b, char* __restrict__ y,
    float* __restrict__ yscale) {
  const int C = 1024;
  size_t row = blockIdx.x;
  int t = threadIdx.x;
  const float4* xr = (const float4*)(x + row * C);
  float4 v = xr[t];
  float s = v.x + v.y + v.z + v.w;
  float s2 = v.x * v.x + v.y * v.y + v.z * v.z + v.w * v.w;
#pragma unroll
  for (int off = 1; off < 64; off <<= 1) {
    s += __shfl_xor(s, off, 64);
    s2 += __shfl_xor(s2, off, 64);
  }
  __shared__ float ps[4], ps2[4], pm[4];
  int wave = t >> 6, lane = t & 63;
  if (lane == 0) { ps[wave] = s; ps2[wave] = s2; }
  __syncthreads();
  s = ps[0] + ps[1] + ps[2] + ps[3];
  s2 = ps2[0] + ps2[1] + ps2[2] + ps2[3];
  float mu = s * (1.0f / C);
  float var = s2 * (1.0f / C) - mu * mu;
  float rstd = rsqrtf(var + 1e-5f);
  float4 gv = ((const float4*)g)[t];
  float4 bv = ((const float4*)b)[t];
  float o0 = (v.x - mu) * rstd * gv.x + bv.x;
  float o1 = (v.y - mu) * rstd * gv.y + bv.y;
  float o2 = (v.z - mu) * rstd * gv.z + bv.z;
  float o3 = (v.w - mu) * rstd * gv.w + bv.w;
  float mx = fmaxf(fmaxf(fabsf(o0), fabsf(o1)), fmaxf(fabsf(o2), fabsf(o3)));
#pragma unroll
  for (int off = 1; off < 64; off <<= 1) mx = fmaxf(mx, __shfl_xor(mx, off, 64));
  if (lane == 0) pm[wave] = mx;
  __syncthreads();
  mx = fmaxf(fmaxf(pm[0], pm[1]), fmaxf(pm[2], pm[3]));
  mx = fmaxf(mx, 1e-20f);
  float inv = 127.0f / mx;
  int q0 = (int)rintf(o0 * inv), q1 = (int)rintf(o1 * inv);
  int q2 = (int)rintf(o2 * inv), q3 = (int)rintf(o3 * inv);
  unsigned pk = ((unsigned)(q0 & 0xff)) | ((unsigned)(q1 & 0xff) << 8) |
                ((unsigned)(q2 & 0xff) << 16) | ((unsigned)(q3 & 0xff) << 24);
  ((unsigned*)(y + row * C))[t] = pk;
  if (t == 0) yscale[row] = mx * (1.0f / 127.0f);
}

// -------- QK^T GEMM, pipelined: S[p][x] = fp16((q.k/32)*c[x]) --------
// 128x128 tile, 256 thr (4 waves 2x2), BK=32, TRIPLE-buffered LDS, prefetch
// distance 2, raw s_barrier + manual s_waitcnt vmcnt(4) so the next-next
// stage's global_load_lds stays in flight across the barrier.
__global__ __launch_bounds__(256) void gemm_qk_pipe(
    const _Float16* __restrict__ A,   // [B][1024][1024] q16
    const _Float16* __restrict__ Bm,  // [B][8192][1024] k16
    _Float16* __restrict__ Sm,        // [B][1024][8192]
    const float* __restrict__ conf)   // [B][8192]
{
  const int N = 8192, K = 1024, NSTG = 32;
  int bz = blockIdx.z;
  const _Float16* Ab = A + (size_t)bz * 1024 * K;
  const _Float16* Bb = Bm + (size_t)bz * (size_t)N * K;
  _Float16* Sb = Sm + (size_t)bz * 1024 * N;

  __shared__ _Float16 lA[3 * 4096];  // 3 x 8 KB
  __shared__ _Float16 lB[3 * 4096];  // 3 x 8 KB

  int tid = threadIdx.x;
  int wave = tid >> 6, lane = tid & 63;
  int wm = wave >> 1, wn = wave & 1;
  int m0 = blockIdx.y * 128, n0 = blockIdx.x * 128;

  f32x4 acc[4][4];
  f32x4 zero = {0.f, 0.f, 0.f, 0.f};
#pragma unroll
  for (int i = 0; i < 4; ++i)
#pragma unroll
    for (int j = 0; j < 4; ++j) acc[i][j] = zero;

  // staging: 128 rows x 4 kg per operand = 512 segs; 256 thr -> 2 each
  int rS = tid & 127, kg0 = tid >> 7, kg1 = kg0 + 2;
  const _Float16* gA0 = Ab + (size_t)(m0 + rS) * K + kg0 * 8;
  const _Float16* gA1 = Ab + (size_t)(m0 + rS) * K + kg1 * 8;
  const _Float16* gB0 = Bb + (size_t)(n0 + rS) * K + kg0 * 8;
  const _Float16* gB1 = Bb + (size_t)(n0 + rS) * K + kg1 * 8;
  int d0 = kg0 * 1024 + rS * 8;
  int d1 = kg1 * 1024 + rS * 8;

  // prologue: stages 0,1 -> bufs 0,1
  gll16(gA0, &lA[d0]); gll16(gA1, &lA[d1]);
  gll16(gB0, &lB[d0]); gll16(gB1, &lB[d1]);
  gll16(gA0 + 32, &lA[4096 + d0]); gll16(gA1 + 32, &lA[4096 + d1]);
  gll16(gB0 + 32, &lB[4096 + d0]); gll16(gB1 + 32, &lB[4096 + d1]);

  int kg = lane >> 4, lr = lane & 15;
  int bfc = 0;   // compute buffer
  int bfi = 2;   // issue buffer (stage k+2)

  for (int k = 0; k < NSTG; ++k) {
    // wait until stage k's 4 loads landed; stage k+1's 4 may remain in flight
    if (k <= NSTG - 3)
      __builtin_amdgcn_s_waitcnt(0xF74);  // vmcnt(4), lgkm/exp unrestricted
    else
      __builtin_amdgcn_s_waitcnt(0xF70);  // vmcnt(0) for tail stages
    __builtin_amdgcn_s_barrier();
    __builtin_amdgcn_sched_barrier(0);
    if (k <= NSTG - 3) {
      int kk = (k + 2) * 32;
      int bo = bfi * 4096;
      gll16(gA0 + kk, &lA[bo + d0]); gll16(gA1 + kk, &lA[bo + d1]);
      gll16(gB0 + kk, &lB[bo + d0]); gll16(gB1 + kk, &lB[bo + d1]);
    }
    const _Float16* la = &lA[bfc * 4096];
    const _Float16* lb = &lB[bfc * 4096];
    half8 af[4], bfr[4];
#pragma unroll
    for (int t = 0; t < 4; ++t) {
      af[t] = *(const half8*)&la[kg * 1024 + (wm * 64 + t * 16 + lr) * 8];
      bfr[t] = *(const half8*)&lb[kg * 1024 + (wn * 64 + t * 16 + lr) * 8];
    }
#pragma unroll
    for (int t = 0; t < 4; ++t)
#pragma unroll
      for (int u = 0; u < 4; ++u)
        acc[t][u] = __builtin_amdgcn_mfma_f32_16x16x32_f16(af[t], bfr[u], acc[t][u], 0, 0, 0);
    __builtin_amdgcn_sched_barrier(0);
    bfc = (bfc == 2) ? 0 : bfc + 1;
    bfi = (bfi == 2) ? 0 : bfi + 1;
  }

  int cq = lane >> 4, cn = lane & 15;
  const float* cb = conf + (size_t)bz * N;
#pragma unroll
  for (int u = 0; u < 4; ++u) {
    int gn = n0 + wn * 64 + u * 16 + cn;
    float cs = 0.03125f * cb[gn];
#pragma unroll
    for (int t = 0; t < 4; ++t) {
      int gm = m0 + wm * 64 + t * 16 + cq * 4;
#pragma unroll
      for (int r = 0; r < 4; ++r)
        Sb[(size_t)(gm + r) * N + gn] = (_Float16)(acc[t][u][r] * cs);
    }
  }
}

// ------- softmax over X=8192 (fp16 S) + threshold + renorm + compact (x, w) -------
__global__ __launch_bounds__(256) void softmax_compact(
    const _Float16* __restrict__ S, unsigned* __restrict__ entries,
    int* __restrict__ counts) {
  const int X = 8192;
  size_t row = blockIdx.x;
  const half8* sr = (const half8*)(S + row * X);
  int t = threadIdx.x;
  int wave = t >> 6, lane = t & 63;
  __shared__ float sh[4];
  __shared__ int scnt;

  float v[32];
#pragma unroll
  for (int j = 0; j < 4; ++j) {
    half8 h = sr[t + j * 256];
#pragma unroll
    for (int c = 0; c < 8; ++c) v[j * 8 + c] = (float)h[c];
  }

  float m = -1e30f;
#pragma unroll
  for (int i = 0; i < 32; ++i) m = fmaxf(m, v[i]);
#pragma unroll
  for (int off = 1; off < 64; off <<= 1) m = fmaxf(m, __shfl_xor(m, off, 64));
  if (lane == 0) sh[wave] = m;
  __syncthreads();
  m = fmaxf(fmaxf(sh[0], sh[1]), fmaxf(sh[2], sh[3]));
  __syncthreads();

  float l = 0.f;
#pragma unroll
  for (int i = 0; i < 32; ++i) {
    v[i] = __expf(v[i] - m);
    l += v[i];
  }
#pragma unroll
  for (int off = 1; off < 64; off <<= 1) l += __shfl_xor(l, off, 64);
  if (lane == 0) sh[wave] = l;
  __syncthreads();
  l = sh[0] + sh[1] + sh[2] + sh[3];
  __syncthreads();

  float thr = 0.0005f * l;
  float ks = 0.f;
#pragma unroll
  for (int i = 0; i < 32; ++i) {
    v[i] = (v[i] >= thr) ? v[i] : 0.f;
    ks += v[i];
  }
#pragma unroll
  for (int off = 1; off < 64; off <<= 1) ks += __shfl_xor(ks, off, 64);
  if (lane == 0) sh[wave] = ks;
  __syncthreads();
  if (t == 0) scnt = 0;
  __syncthreads();
  ks = sh[0] + sh[1] + sh[2] + sh[3];

  float inv = 1.0f / ks;
  unsigned* er = entries + row * 2048;
#pragma unroll
  for (int j = 0; j < 4; ++j) {
#pragma unroll
    for (int c = 0; c < 8; ++c) {
      float val = v[j * 8 + c];
      if (val > 0.f) {
        int pos = atomicAdd(&scnt, 1);
        _Float16 h = (_Float16)(val * inv);
        unsigned short hb;
        __builtin_memcpy(&hb, &h, 2);
        er[pos] = ((unsigned)((t + j * 256) * 8 + c) << 16) | hb;
      }
    }
  }
  __syncthreads();
  if (t == 0) counts[row] = scnt;
}

__device__ __forceinline__ void acc4(float* a, unsigned w, float wt) {
  a[0] += wt * (float)(signed char)(w & 0xff);
  a[1] += wt * (float)(signed char)((w >> 8) & 0xff);
  a[2] += wt * (float)(signed char)((w >> 16) & 0xff);
  a[3] += wt * (float)(signed char)(w >> 24);
}

// --- sparse gather (int8 v): out[row] = feat[row] + sum w*scale[x]*v8[x] ---
// 512 threads = 8 entry-streams (one per wave) x 64 lanes x 16 B.
__global__ __launch_bounds__(512) void gather_pv_i8(
    const unsigned* __restrict__ entries, const int* __restrict__ counts,
    const char* __restrict__ v8, const float* __restrict__ vscale,
    const float* __restrict__ feat, float* __restrict__ out) {
  const int X = 8192, C = 1024;
  int row = blockIdx.x;  // b*1024 + p
  int b = row >> 10;
  int t = threadIdx.x;
  int s = t >> 6;         // stream = wave 0..7
  int lane = t & 63;
  int c = lane * 16;      // byte offset within v-row

  __shared__ unsigned se[2048];
  __shared__ float red[8][1028];

  int cnt = counts[row];
  const unsigned* er = entries + (size_t)row * 2048;
  for (int i = t; i < cnt; i += 512) se[i] = er[i];
  __syncthreads();

  const char* vb = v8 + (size_t)b * X * C;
  const float* sb = vscale + (size_t)b * X;
  float a[16];
#pragma unroll
  for (int i = 0; i < 16; ++i) a[i] = 0.f;

#pragma unroll 2
  for (int j = s; j < cnt; j += 8) {
    unsigned e = se[j];
    int x = e >> 16;
    float w = h2f((unsigned short)(e & 0xffff)) * sb[x];
    uint4 pv = *(const uint4*)(vb + (size_t)x * C + c);
    acc4(a + 0, pv.x, w);
    acc4(a + 4, pv.y, w);
    acc4(a + 8, pv.z, w);
    acc4(a + 12, pv.w, w);
  }
  float* rp = &red[s][c];
#pragma unroll
  for (int i = 0; i < 16; ++i) rp[i] = a[i];
  __syncthreads();

  int p = t * 2;
  float2 f = *(const float2*)(feat + (size_t)row * C + p);
  float o0 = f.x, o1 = f.y;
#pragma unroll
  for (int ss = 0; ss < 8; ++ss) {
    o0 += red[ss][p];
    o1 += red[ss][p + 1];
  }
  float2 o = {o0, o1};
  *(float2*)(out + (size_t)row * C + p) = o;
}

extern "C" void kernel_launch(void* const* d_in, const int* in_sizes, int n_in,
                              void* d_out, int out_size, void* d_ws, size_t ws_size,
                              hipStream_t stream) {
  const int B = 4, P = 1024, X = 8192, C = 1024;
  const float* feat  = (const float*)d_in[0];
  const float* mem_k = (const float*)d_in[1];
  const float* mem_v = (const float*)d_in[2];
  const float* mem_c = (const float*)d_in[3];  // [B,X,1] -> flat [B*X]
  const float* g_q = (const float*)d_in[5];
  const float* b_q = (const float*)d_in[6];
  const float* g_k = (const float*)d_in[7];
  const float* b_k = (const float*)d_in[8];
  const float* g_v = (const float*)d_in[9];
  const float* b_v = (const float*)d_in[10];

  char* ws = (char*)d_ws;
  const size_t MB = 1024 * 1024;
  _Float16* q16 = (_Float16*)(ws + 0);             // 8 MB   [B][P][C]
  _Float16* k16 = (_Float16*)(ws + 8 * MB);        // 64 MB  [B][X][C]
  _Float16* S   = (_Float16*)(ws + 72 * MB);       // 64 MB  [B][P][X]
  char*     v8  = (char*)(ws + 136 * MB);          // 32 MB  [B][X][C] int8
  float* vscale = (float*)(ws + 168 * MB);         // 128 KB [B*X]
  unsigned* entries = (unsigned*)(ws + 169 * MB);  // 32 MB  [B*P][2048]
  int*      counts  = (int*)(ws + 201 * MB);       // 16 KB  [B*P]

  ln_cast_f16<<<B * P, 256, 0, stream>>>(feat, g_q, b_q, q16);
  ln_cast_f16<<<B * X, 256, 0, stream>>>(mem_k, g_k, b_k, k16);
  ln_cast_i8<<<B * X, 256, 0, stream>>>(mem_v, g_v, b_v, v8, vscale);
  gemm_qk_pipe<<<dim3(X / 128, P / 128, B), 256, 0, stream>>>(q16, k16, S, mem_c);
  softmax_compact<<<B * P, 256, 0, stream>>>(S, entries, counts);
  gather_pv_i8<<<B * P, 512, 0, stream>>>(entries, counts, v8, vscale, feat,
                                          (float*)d_out);
}